// Round 6
// baseline (358.050 us; speedup 1.0000x reference)
//
#include <hip/hip_runtime.h>

#define NN 50000
#define NE 640000
#define RB ((NN + 255) / 256)   // 196 scan blocks

struct __align__(8) edge_t { int r; float w; };

// ---- detect whether edge_index arrived as int64 or int32 ----
__global__ void k_detect(const unsigned* __restrict__ w, int* __restrict__ flag) {
    __shared__ int found;
    if (threadIdx.x == 0) found = 0;
    __syncthreads();
    int j = threadIdx.x * 2499;          // j < 640000
    if (w[2 * j + 1] != 0u) atomicAdd(&found, 1);
    __syncthreads();
    if (threadIdx.x == 0) *flag = (found == 0) ? 1 : 0;
}

__device__ __forceinline__ int edge_at(const void* p, long long i, int m64) {
    if (m64) return (int)((const long long*)p)[i];
    return ((const int*)p)[i];
}

// ---- count in-degree (col side, excluding self-loops) ----
__global__ void k_count(const void* __restrict__ e, const int* __restrict__ flag,
                        int* __restrict__ deg) {
    int i = blockIdx.x * 256 + threadIdx.x;
    if (i >= NE) return;
    int m = *flag;
    int c = edge_at(e, (long long)NE + i, m);
    if ((unsigned)c < (unsigned)NN) atomicAdd(&deg[c], 1);
}

// ---- two-level scan: per-block reduce -> tiny scan -> per-block apply ----
__global__ __launch_bounds__(256) void k_reduce(const int* __restrict__ deg,
                                                int* __restrict__ bsum) {
    __shared__ int s[256];
    int i = blockIdx.x * 256 + threadIdx.x;
    s[threadIdx.x] = (i < NN) ? deg[i] : 0;
    __syncthreads();
    for (int d = 128; d > 0; d >>= 1) {
        if (threadIdx.x < d) s[threadIdx.x] += s[threadIdx.x + d];
        __syncthreads();
    }
    if (threadIdx.x == 0) bsum[blockIdx.x] = s[0];
}

__global__ __launch_bounds__(256) void k_scanb(const int* __restrict__ bsum,
                                               int* __restrict__ bpref) {
    __shared__ int s[256];
    int t = threadIdx.x;
    s[t] = (t < RB) ? bsum[t] : 0;
    __syncthreads();
    for (int d = 1; d < 256; d <<= 1) {
        int v = (t >= d) ? s[t - d] : 0;
        __syncthreads();
        s[t] += v;
        __syncthreads();
    }
    if (t < RB) bpref[t] = (t == 0) ? 0 : s[t - 1];
}

__global__ __launch_bounds__(256) void k_apply(const int* __restrict__ deg,
                                               const int* __restrict__ bpref,
                                               int* __restrict__ offs,
                                               int* __restrict__ cursor,
                                               float* __restrict__ dinv) {
    __shared__ int s[256];
    int t = threadIdx.x;
    int i = blockIdx.x * 256 + t;
    int dg = (i < NN) ? deg[i] : 0;
    s[t] = dg;
    __syncthreads();
    for (int d = 1; d < 256; d <<= 1) {
        int v = (t >= d) ? s[t - d] : 0;
        __syncthreads();
        s[t] += v;
        __syncthreads();
    }
    if (i < NN) {
        int excl = bpref[blockIdx.x] + s[t] - dg;
        offs[i] = excl;
        cursor[i] = excl;
        dinv[i] = rsqrtf((float)(dg + 1));   // +1 self-loop
        if (i == NN - 1) offs[NN] = excl + dg;
    }
}

// ---- scatter edges into CSR buckets; per-edge (src, dinv[src]) packed 8B ----
__global__ void k_scatter(const void* __restrict__ e, const int* __restrict__ flag,
                          int* __restrict__ cursor, edge_t* __restrict__ ew,
                          const float* __restrict__ dinv) {
    int i = blockIdx.x * 256 + threadIdx.x;
    if (i >= NE) return;
    int m = *flag;
    int c = edge_at(e, (long long)NE + i, m);
    if ((unsigned)c >= (unsigned)NN) return;
    int r = edge_at(e, (long long)i, m);
    r = min(max(r, 0), NN - 1);
    int p = atomicAdd(&cursor[c], 1);
    edge_t t2; t2.r = r; t2.w = dinv[r];
    ew[p] = t2;
}

// ---- GEMM: T[N,128] = A[N,128] @ W[128,128]; W in LDS, 8x8 register tile ----
__global__ __launch_bounds__(256) void k_gemm128(const float* __restrict__ A,
                                                 const float* __restrict__ W,
                                                 float* __restrict__ T) {
    __shared__ float Ws[128 * 128];
    int t = threadIdx.x;
#pragma unroll
    for (int i = 0; i < 16; i++)
        ((float4*)Ws)[t + 256 * i] = ((const float4*)W)[t + 256 * i];
    __syncthreads();
    int rg = t >> 4, cg = t & 15;
    int row0 = blockIdx.x * 128 + rg * 8;
    const float* a0 = A + (long long)min(row0 + 0, NN - 1) * 128;
    const float* a1 = A + (long long)min(row0 + 1, NN - 1) * 128;
    const float* a2 = A + (long long)min(row0 + 2, NN - 1) * 128;
    const float* a3 = A + (long long)min(row0 + 3, NN - 1) * 128;
    const float* a4 = A + (long long)min(row0 + 4, NN - 1) * 128;
    const float* a5 = A + (long long)min(row0 + 5, NN - 1) * 128;
    const float* a6 = A + (long long)min(row0 + 6, NN - 1) * 128;
    const float* a7 = A + (long long)min(row0 + 7, NN - 1) * 128;
    float acc[8][8];
#pragma unroll
    for (int i = 0; i < 8; i++)
#pragma unroll
        for (int j = 0; j < 8; j++) acc[i][j] = 0.f;
#pragma unroll 2
    for (int k = 0; k < 128; k++) {
        float4 w0 = *(const float4*)&Ws[k * 128 + cg * 4];
        float4 w1 = *(const float4*)&Ws[k * 128 + cg * 4 + 64];
        float a[8] = {a0[k], a1[k], a2[k], a3[k], a4[k], a5[k], a6[k], a7[k]};
#pragma unroll
        for (int i = 0; i < 8; i++) {
            acc[i][0] += a[i] * w0.x; acc[i][1] += a[i] * w0.y;
            acc[i][2] += a[i] * w0.z; acc[i][3] += a[i] * w0.w;
            acc[i][4] += a[i] * w1.x; acc[i][5] += a[i] * w1.y;
            acc[i][6] += a[i] * w1.z; acc[i][7] += a[i] * w1.w;
        }
    }
#pragma unroll
    for (int i = 0; i < 8; i++) {
        int row = row0 + i;
        if (row < NN) {
            float4 v0 = {acc[i][0], acc[i][1], acc[i][2], acc[i][3]};
            float4 v1 = {acc[i][4], acc[i][5], acc[i][6], acc[i][7]};
            *(float4*)&T[(long long)row * 128 + cg * 4] = v0;
            *(float4*)&T[(long long)row * 128 + cg * 4 + 64] = v1;
        }
    }
}

// ---- final GEMM with bias: out[N,64] = A[N,128] @ W[128,64] + b; 8x4 tile ----
__global__ __launch_bounds__(256) void k_gemm64(const float* __restrict__ A,
                                                const float* __restrict__ W,
                                                const float* __restrict__ b,
                                                float* __restrict__ T) {
    __shared__ float Ws[128 * 64];
    int t = threadIdx.x;
#pragma unroll
    for (int i = 0; i < 8; i++)
        ((float4*)Ws)[t + 256 * i] = ((const float4*)W)[t + 256 * i];
    __syncthreads();
    int rg = t >> 4, cg = t & 15;
    int row0 = blockIdx.x * 128 + rg * 8;
    const float* a0 = A + (long long)min(row0 + 0, NN - 1) * 128;
    const float* a1 = A + (long long)min(row0 + 1, NN - 1) * 128;
    const float* a2 = A + (long long)min(row0 + 2, NN - 1) * 128;
    const float* a3 = A + (long long)min(row0 + 3, NN - 1) * 128;
    const float* a4 = A + (long long)min(row0 + 4, NN - 1) * 128;
    const float* a5 = A + (long long)min(row0 + 5, NN - 1) * 128;
    const float* a6 = A + (long long)min(row0 + 6, NN - 1) * 128;
    const float* a7 = A + (long long)min(row0 + 7, NN - 1) * 128;
    float acc[8][4];
#pragma unroll
    for (int i = 0; i < 8; i++)
#pragma unroll
        for (int j = 0; j < 4; j++) acc[i][j] = 0.f;
#pragma unroll 2
    for (int k = 0; k < 128; k++) {
        float4 w = *(const float4*)&Ws[k * 64 + cg * 4];
        float a[8] = {a0[k], a1[k], a2[k], a3[k], a4[k], a5[k], a6[k], a7[k]};
#pragma unroll
        for (int i = 0; i < 8; i++) {
            acc[i][0] += a[i] * w.x; acc[i][1] += a[i] * w.y;
            acc[i][2] += a[i] * w.z; acc[i][3] += a[i] * w.w;
        }
    }
    float4 bb = ((const float4*)b)[cg];
#pragma unroll
    for (int i = 0; i < 8; i++) {
        int row = row0 + i;
        if (row < NN) {
            float4 v = {acc[i][0] + bb.x, acc[i][1] + bb.y,
                        acc[i][2] + bb.z, acc[i][3] + bb.w};
            *(float4*)&T[(long long)row * 64 + cg * 4] = v;
        }
    }
}

// ---- aggregation: H[c] = relu(dinv[c]*(sum_e w_e*X[src_e] + dinv[c]*X[c]) + b)
// one wave per node, split into two 32-lane halves; each half gathers a full
// 512B row as float4 (16B/lane) -> 2 edges per VMEM instruction, 8 in flight.
__global__ __launch_bounds__(256) void k_agg(const float* __restrict__ X,
                                             const int* __restrict__ offs,
                                             const edge_t* __restrict__ ew,
                                             const float* __restrict__ dinv,
                                             const float* __restrict__ b,
                                             float* __restrict__ H) {
    int t = threadIdx.x;
    int node = blockIdx.x * 4 + (t >> 6);
    if (node >= NN) return;
    int lane = t & 63;
    int half = lane >> 5;          // 0 or 1
    int l32 = lane & 31;           // feature-quad index
    const float4* X4 = (const float4*)X;
    float dc = dinv[node];
    float4 acc = {0.f, 0.f, 0.f, 0.f};
    if (half == 0) {               // self term once
        float4 s = X4[(long long)node * 32 + l32];
        acc.x = dc * s.x; acc.y = dc * s.y; acc.z = dc * s.z; acc.w = dc * s.w;
    }
    int e0 = offs[node], e1 = offs[node + 1];
    int n = e1 - e0;
    const edge_t* ep = ew + e0;
    int i = half;                  // halves take alternating edges
    for (; i + 6 < n; i += 8) {
        edge_t m0 = ep[i], m1 = ep[i + 2], m2 = ep[i + 4], m3 = ep[i + 6];
        float4 v0 = X4[(long long)m0.r * 32 + l32];
        float4 v1 = X4[(long long)m1.r * 32 + l32];
        float4 v2 = X4[(long long)m2.r * 32 + l32];
        float4 v3 = X4[(long long)m3.r * 32 + l32];
        acc.x += m0.w * v0.x + m1.w * v1.x + m2.w * v2.x + m3.w * v3.x;
        acc.y += m0.w * v0.y + m1.w * v1.y + m2.w * v2.y + m3.w * v3.y;
        acc.z += m0.w * v0.z + m1.w * v1.z + m2.w * v2.z + m3.w * v3.z;
        acc.w += m0.w * v0.w + m1.w * v1.w + m2.w * v2.w + m3.w * v3.w;
    }
    for (; i < n; i += 2) {
        edge_t m = ep[i];
        float4 v = X4[(long long)m.r * 32 + l32];
        acc.x += m.w * v.x; acc.y += m.w * v.y;
        acc.z += m.w * v.z; acc.w += m.w * v.w;
    }
    // combine the two halves (lane ^ 32 holds the partner's partial)
    float4 oth;
    oth.x = __shfl_xor(acc.x, 32);
    oth.y = __shfl_xor(acc.y, 32);
    oth.z = __shfl_xor(acc.z, 32);
    oth.w = __shfl_xor(acc.w, 32);
    float4 bb = ((const float4*)b)[l32];
    float4 o;
    o.x = fmaxf(dc * (acc.x + oth.x) + bb.x, 0.f);
    o.y = fmaxf(dc * (acc.y + oth.y) + bb.y, 0.f);
    o.z = fmaxf(dc * (acc.z + oth.z) + bb.z, 0.f);
    o.w = fmaxf(dc * (acc.w + oth.w) + bb.w, 0.f);
    if (half == 0)
        ((float4*)H)[(long long)node * 32 + l32] = o;
}

extern "C" void kernel_launch(void* const* d_in, const int* in_sizes, int n_in,
                              void* d_out, int out_size, void* d_ws, size_t ws_size,
                              hipStream_t stream) {
    const float* x  = (const float*)d_in[0];
    const void*  ei = d_in[1];
    const float* W1 = (const float*)d_in[2];
    const float* b1 = (const float*)d_in[3];
    const float* W2 = (const float*)d_in[4];
    const float* b2 = (const float*)d_in[5];
    const float* Wl = (const float*)d_in[6];
    const float* bl = (const float*)d_in[7];
    float* out = (float*)d_out;

    char* ws = (char*)d_ws;
    size_t off = 0;
    auto alloc = [&](size_t bytes) {
        void* p = ws + off;
        off += (bytes + 255) & ~(size_t)255;
        return p;
    };
    float*  t0     = (float*)alloc((size_t)NN * 128 * 4);
    float*  t1     = (float*)alloc((size_t)NN * 128 * 4);
    int*    deg    = (int*)alloc((size_t)NN * 4);
    int*    offs   = (int*)alloc((size_t)(NN + 1) * 4);
    int*    cursor = (int*)alloc((size_t)NN * 4);
    edge_t* ewbuf  = (edge_t*)alloc((size_t)NE * 8);
    float*  dinv   = (float*)alloc((size_t)NN * 4);
    int*    bsum   = (int*)alloc((size_t)RB * 4);
    int*    bpref  = (int*)alloc((size_t)RB * 4);
    int*    flag   = (int*)alloc(256);

    hipMemsetAsync(deg, 0, (size_t)NN * 4, stream);
    k_detect<<<1, 256, 0, stream>>>((const unsigned*)ei, flag);
    k_count<<<(NE + 255) / 256, 256, 0, stream>>>(ei, flag, deg);
    k_reduce<<<RB, 256, 0, stream>>>(deg, bsum);
    k_scanb<<<1, 256, 0, stream>>>(bsum, bpref);
    k_apply<<<RB, 256, 0, stream>>>(deg, bpref, offs, cursor, dinv);
    k_scatter<<<(NE + 255) / 256, 256, 0, stream>>>(ei, flag, cursor, ewbuf, dinv);

    int gb = (NN + 127) / 128;
    k_gemm128<<<gb, 256, 0, stream>>>(x, W1, t0);
    k_agg<<<(NN + 3) / 4, 256, 0, stream>>>(t0, offs, ewbuf, dinv, b1, t1);
    k_gemm128<<<gb, 256, 0, stream>>>(t1, W2, t0);
    k_agg<<<(NN + 3) / 4, 256, 0, stream>>>(t0, offs, ewbuf, dinv, b2, t1);
    k_gemm64<<<gb, 256, 0, stream>>>(t1, Wl, bl, out);
}